// Round 5
// baseline (1909.045 us; speedup 1.0000x reference)
//
#include <hip/hip_runtime.h>
#include <math.h>

#define T_STEPS 512
#define BATCH   512

__device__ __forceinline__ float sigmoidf_(float x) {
    return 1.0f / (1.0f + __expf(-x));        // x<<0 -> 1/inf = 0, safe
}
__device__ __forceinline__ float tanhf_(float x) {
    float ax = fabsf(x);
    float e  = __expf(-2.0f * ax);            // in (0,1], never overflows
    float t  = (1.0f - e) / (1.0f + e);
    return copysignf(t, x);
}
__device__ __forceinline__ float4 ld4(const float* p) {
    return make_float4(p[0], p[1], p[2], p[3]);
}

// ---------------------------------------------------------------------------
// gemm1: xg[r][j] = b[j] + sum_k A[r][k]*W[j][k], K=64, N=400.
// Weights in 16 NAMED float4s (no array -> no scratch). 64 rows/block.
// ---------------------------------------------------------------------------
__global__ __launch_bounds__(448, 2) void gemm1_kernel(
    const float* __restrict__ A, const float* __restrict__ W,
    const float* __restrict__ bih, const float* __restrict__ bhh,
    float* __restrict__ xg)
{
    __shared__ __align__(16) float As[64 * 64];
    const int tid = threadIdx.x;

    float4 W00,W01,W02,W03,W04,W05,W06,W07,W08,W09,W10,W11,W12,W13,W14,W15;
    float bias = 0.0f;
    if (tid < 400) {
        bias = bih[tid] + bhh[tid];
        const float* wp = W + tid * 64;
        W00=ld4(wp+ 0); W01=ld4(wp+ 4); W02=ld4(wp+ 8); W03=ld4(wp+12);
        W04=ld4(wp+16); W05=ld4(wp+20); W06=ld4(wp+24); W07=ld4(wp+28);
        W08=ld4(wp+32); W09=ld4(wp+36); W10=ld4(wp+40); W11=ld4(wp+44);
        W12=ld4(wp+48); W13=ld4(wp+52); W14=ld4(wp+56); W15=ld4(wp+60);
    }

    const size_t r0 = (size_t)blockIdx.x * 64;
    const float4* Ag = (const float4*)(A + r0 * 64);
    float4* As4 = (float4*)As;
    for (int i = tid; i < 64 * 16; i += 448) As4[i] = Ag[i];
    __syncthreads();

    if (tid < 400) {
        for (int r = 0; r < 64; ++r) {
            const float4* a4 = (const float4*)(As + r * 64);
            float a0 = bias, a1 = 0.0f;
#define G1V(WV, I) { float4 v = a4[I]; \
            a0 = fmaf(v.x, WV.x, a0); a1 = fmaf(v.y, WV.y, a1); \
            a0 = fmaf(v.z, WV.z, a0); a1 = fmaf(v.w, WV.w, a1); }
            G1V(W00,0) G1V(W01,1) G1V(W02,2) G1V(W03,3)
            G1V(W04,4) G1V(W05,5) G1V(W06,6) G1V(W07,7)
            G1V(W08,8) G1V(W09,9) G1V(W10,10) G1V(W11,11)
            G1V(W12,12) G1V(W13,13) G1V(W14,14) G1V(W15,15)
#undef G1V
            xg[(r0 + r) * 400 + tid] = a0 + a1;
        }
    }
}

// ---------------------------------------------------------------------------
// gemm2: K=100, N=200, split-K (q-halves 52/48), weights in 13 NAMED float4s
// per slot (q=1's 13th vec is zero, matching zeroed LDS row pad [100..103]).
// ---------------------------------------------------------------------------
__global__ __launch_bounds__(448, 2) void gemm2_kernel(
    const float* __restrict__ A,      // [rows,100] = h1 chunk
    const float* __restrict__ W,      // [200,100]  = w_ih2
    const float* __restrict__ bih, const float* __restrict__ bhh,
    float* __restrict__ xg)           // [rows,200]
{
    __shared__ __align__(16) float As[64 * 104];
    __shared__ __align__(16) float ps[8][2][200];

    const int tid  = threadIdx.x;
    const bool slot = (tid < 400);
    const int q = slot ? tid / 200 : 0;
    const int j = slot ? tid % 200 : 0;

    float4 W00,W01,W02,W03,W04,W05,W06,W07,W08,W09,W10,W11,W12;
    float bias = 0.0f;
    if (slot) {
        if (q == 0) bias = bih[j] + bhh[j];
        const float* wp = W + j * 100 + q * 52;
        W00=ld4(wp+ 0); W01=ld4(wp+ 4); W02=ld4(wp+ 8); W03=ld4(wp+12);
        W04=ld4(wp+16); W05=ld4(wp+20); W06=ld4(wp+24); W07=ld4(wp+28);
        W08=ld4(wp+32); W09=ld4(wp+36); W10=ld4(wp+40); W11=ld4(wp+44);
        W12 = q ? make_float4(0.f,0.f,0.f,0.f) : ld4(wp+48);
    }

    const size_t r0 = (size_t)blockIdx.x * 64;
    const float2* A2 = (const float2*)(A + r0 * 100);
    float2* As2 = (float2*)As;
    for (int i = tid; i < 64 * 50; i += 448) {
        int r = i / 50, k2 = i % 50;
        As2[r * 52 + k2] = A2[i];
    }
    if (tid < 64) {
        As[tid*104+100]=0.f; As[tid*104+101]=0.f;
        As[tid*104+102]=0.f; As[tid*104+103]=0.f;
    }
    __syncthreads();

    const float4* As4 = (const float4*)As;
    const int q13 = q * 13;
    const float base = (q == 0) ? bias : 0.0f;
    for (int g = 0; g < 8; ++g) {
        const int rb = g * 8;
        if (slot) {
#define G2V(P, WV, I) { float4 v = P[I]; \
            A0 = fmaf(v.x, WV.x, A0); A1 = fmaf(v.y, WV.y, A1); \
            A0 = fmaf(v.z, WV.z, A0); A1 = fmaf(v.w, WV.w, A1); }
#define G2ROW(RR) { const float4* a4 = As4 + (rb + RR) * 26 + q13; \
            float A0 = base, A1 = 0.0f; \
            G2V(a4,W00,0) G2V(a4,W01,1) G2V(a4,W02,2) G2V(a4,W03,3) \
            G2V(a4,W04,4) G2V(a4,W05,5) G2V(a4,W06,6) G2V(a4,W07,7) \
            G2V(a4,W08,8) G2V(a4,W09,9) G2V(a4,W10,10) G2V(a4,W11,11) \
            G2V(a4,W12,12) \
            ps[RR][q][j] = A0 + A1; }
            G2ROW(0) G2ROW(1) G2ROW(2) G2ROW(3)
            G2ROW(4) G2ROW(5) G2ROW(6) G2ROW(7)
#undef G2ROW
#undef G2V
        }
        __syncthreads();
        if (tid < 200) {
            #pragma unroll
            for (int rr = 0; rr < 8; ++rr)
                xg[(r0 + rb + rr) * 200 + tid] = ps[rr][0][tid] + ps[rr][1][tid];
        }
        __syncthreads();
    }
}

// ---------------------------------------------------------------------------
// scan1: layer-1 recurrence. 256 blocks (2 batch rows, 1/CU), 832 threads.
//   tid 0..415   : slots q=0 (j=tid,     w_hh1[j][0:52] in 13 named vecs)
//   tid 416..815 : slots q=1 (j=tid-416, w_hh1[j][52:100] in 12 vecs + zero)
//   tid 0..199   : update threads (bn=tid/100, u=tid%100), c in register
// h in LDS h_s[2][104] (pad=0), partials ps[2][2][400] (stride-1, no
// bank conflicts).
// ---------------------------------------------------------------------------
__global__ __launch_bounds__(832, 3) void scan1_kernel(
    const float* __restrict__ xg,     // [CH*B, 400] chunk-local
    const float* __restrict__ w_hh,   // [400, 100]
    float* __restrict__ h1c,          // [CH*B, 100] chunk-local
    float* __restrict__ c1state,      // [B, 100]
    int t0, int CH)
{
    __shared__ __align__(16) float h_s[2][104];
    __shared__ __align__(16) float ps[2][2][400];

    const int tid   = threadIdx.x;
    const int q     = (tid >= 416) ? 1 : 0;
    const int j     = tid - 416 * q;
    const bool slot = (j < 400);
    const int brow0 = blockIdx.x * 2;

    float4 W00,W01,W02,W03,W04,W05,W06,W07,W08,W09,W10,W11,W12;
    if (slot) {
        const float* wp = w_hh + j * 100 + q * 52;
        W00=ld4(wp+ 0); W01=ld4(wp+ 4); W02=ld4(wp+ 8); W03=ld4(wp+12);
        W04=ld4(wp+16); W05=ld4(wp+20); W06=ld4(wp+24); W07=ld4(wp+28);
        W08=ld4(wp+32); W09=ld4(wp+36); W10=ld4(wp+40); W11=ld4(wp+44);
        W12 = q ? make_float4(0.f,0.f,0.f,0.f) : ld4(wp+48);
    }

    float c = 0.0f;
    if (tid < 200) {
        int bn = tid / 100, u = tid % 100;
        if (t0 == 0) {
            h_s[bn][u] = 0.0f;
        } else {
            h_s[bn][u] = h1c[((size_t)(CH - 1) * BATCH + brow0 + bn) * 100 + u];
            c          = c1state[(size_t)(brow0 + bn) * 100 + u];
        }
    }
    if (tid >= 200 && tid < 208) {          // zero the float4 pad [100..103]
        int i = tid - 200;
        h_s[i >> 2][100 + (i & 3)] = 0.0f;
    }

    float xgv0 = 0.0f, xgv1 = 0.0f;
    if (slot && q == 0) {
        xgv0 = xg[(size_t)brow0 * 400 + j];
        xgv1 = xg[((size_t)brow0 + 1) * 400 + j];
    }
    __syncthreads();

    const int hq = q * 13;
    for (int tl = 0; tl < CH; ++tl) {
        float pre0 = 0.0f, pre1 = 0.0f;
        if (slot && q == 0 && tl + 1 < CH) {
            pre0 = xg[((size_t)(tl + 1) * BATCH + brow0) * 400 + j];
            pre1 = xg[((size_t)(tl + 1) * BATCH + brow0 + 1) * 400 + j];
        }
        if (slot) {
            const float4* h0 = (const float4*)h_s[0] + hq;
            const float4* h1 = (const float4*)h_s[1] + hq;
            float a00 = xgv0, a01 = 0.0f, a10 = xgv1, a11 = 0.0f;
#define S1ACC(WV, I) { float4 v0 = h0[I], v1 = h1[I]; \
            a00 = fmaf(v0.x, WV.x, a00); a10 = fmaf(v1.x, WV.x, a10); \
            a01 = fmaf(v0.y, WV.y, a01); a11 = fmaf(v1.y, WV.y, a11); \
            a00 = fmaf(v0.z, WV.z, a00); a10 = fmaf(v1.z, WV.z, a10); \
            a01 = fmaf(v0.w, WV.w, a01); a11 = fmaf(v1.w, WV.w, a11); }
            S1ACC(W00,0) S1ACC(W01,1) S1ACC(W02,2) S1ACC(W03,3)
            S1ACC(W04,4) S1ACC(W05,5) S1ACC(W06,6) S1ACC(W07,7)
            S1ACC(W08,8) S1ACC(W09,9) S1ACC(W10,10) S1ACC(W11,11)
            S1ACC(W12,12)
#undef S1ACC
            ps[0][q][j] = a00 + a01;
            ps[1][q][j] = a10 + a11;
        }
        __syncthreads();
        xgv0 = pre0; xgv1 = pre1;
        if (tid < 200) {
            int bn = tid / 100, u = tid % 100;
            float gi = ps[bn][0][u]       + ps[bn][1][u];
            float gf = ps[bn][0][100 + u] + ps[bn][1][100 + u];
            float gg = ps[bn][0][200 + u] + ps[bn][1][200 + u];
            float go = ps[bn][0][300 + u] + ps[bn][1][300 + u];
            c = sigmoidf_(gf) * c + sigmoidf_(gi) * tanhf_(gg);
            float h = sigmoidf_(go) * tanhf_(c);
            h_s[bn][u] = h;
            h1c[((size_t)tl * BATCH + brow0 + bn) * 100 + u] = h;
        }
        __syncthreads();
    }
    if (tid < 200) {
        int bn = tid / 100, u = tid % 100;
        c1state[(size_t)(brow0 + bn) * 100 + u] = c;
    }
}

// ---------------------------------------------------------------------------
// scan23: layers 2+3 + linear, pipelined; weights in NAMED vecs (13 + 7).
// ---------------------------------------------------------------------------
__global__ __launch_bounds__(384, 2) void scan23_kernel(
    const float* __restrict__ xg2,    // [CH*B, 200] chunk-local (biases folded)
    const float* __restrict__ w_hh2,  // [200, 50]
    const float* __restrict__ w_ih3,  // [100, 50]
    const float* __restrict__ w_hh3,  // [100, 25]
    const float* __restrict__ b_ih3, const float* __restrict__ b_hh3,
    const float* __restrict__ w_lin, const float* __restrict__ b_lin,
    float* __restrict__ out,          // [T*B]
    float* __restrict__ h2state, float* __restrict__ c2state,  // [B,50]
    float* __restrict__ h3state, float* __restrict__ c3state,  // [B,25]
    int t0, int CH)
{
    __shared__ __align__(16) float h2_s[52];
    __shared__ __align__(16) float x3_s[2][52];
    __shared__ __align__(16) float h3_s[28];
    __shared__ __align__(16) float h3o_s[2][28];
    __shared__ __align__(16) float g2_s[200];
    __shared__ __align__(16) float g3_s[100];

    const int tid  = threadIdx.x;
    const int brow = blockIdx.x;

    float4 WA0,WA1,WA2,WA3,WA4,WA5,WA6,WA7,WA8,WA9,WA10,WA11,WA12;
    float4 WB0,WB1,WB2,WB3,WB4,WB5,WB6;
    float bias = 0.0f;

    if (tid < 200) {                       // L2 gates: w_hh2 row (50 + 2 zeros)
        const float* p = w_hh2 + tid * 50;
        WA0=ld4(p+ 0); WA1=ld4(p+ 4); WA2=ld4(p+ 8); WA3=ld4(p+12);
        WA4=ld4(p+16); WA5=ld4(p+20); WA6=ld4(p+24); WA7=ld4(p+28);
        WA8=ld4(p+32); WA9=ld4(p+36); WA10=ld4(p+40); WA11=ld4(p+44);
        WA12 = make_float4(p[48], p[49], 0.f, 0.f);
    } else if (tid >= 256 && tid < 356) {  // L3 gates
        int jj = tid - 256;
        bias = b_ih3[jj] + b_hh3[jj];
        const float* p = w_ih3 + jj * 50;
        WA0=ld4(p+ 0); WA1=ld4(p+ 4); WA2=ld4(p+ 8); WA3=ld4(p+12);
        WA4=ld4(p+16); WA5=ld4(p+20); WA6=ld4(p+24); WA7=ld4(p+28);
        WA8=ld4(p+32); WA9=ld4(p+36); WA10=ld4(p+40); WA11=ld4(p+44);
        WA12 = make_float4(p[48], p[49], 0.f, 0.f);
        const float* p2 = w_hh3 + jj * 25;
        WB0=ld4(p2+ 0); WB1=ld4(p2+ 4); WB2=ld4(p2+ 8);
        WB3=ld4(p2+12); WB4=ld4(p2+16); WB5=ld4(p2+20);
        WB6 = make_float4(p2[24], 0.f, 0.f, 0.f);
    } else if (tid == 370) {               // linear (7 vecs in WA0..WA6)
        bias = b_lin[0];
        WA0=ld4(w_lin+ 0); WA1=ld4(w_lin+ 4); WA2=ld4(w_lin+ 8);
        WA3=ld4(w_lin+12); WA4=ld4(w_lin+16); WA5=ld4(w_lin+20);
        WA6 = make_float4(w_lin[24], 0.f, 0.f, 0.f);
    }

    float c2 = 0.0f, c3 = 0.0f;
    if (tid < 52)  { h2_s[tid] = 0.0f; x3_s[0][tid] = 0.0f; x3_s[1][tid] = 0.0f; }
    if (tid >= 52 && tid < 80)  h3_s[tid - 52] = 0.0f;
    if (tid >= 80 && tid < 108) h3o_s[0][tid - 80] = 0.0f;
    if (tid >= 108 && tid < 136) h3o_s[1][tid - 108] = 0.0f;
    __syncthreads();
    if (t0 > 0) {
        if (tid < 50) {
            h2_s[tid] = h2state[(size_t)brow * 50 + tid];
            c2        = c2state[(size_t)brow * 50 + tid];
        }
        if (tid >= 256 && tid < 281) {
            int u = tid - 256;
            h3_s[u] = h3state[(size_t)brow * 25 + u];
            c3      = c3state[(size_t)brow * 25 + u];
        }
    }
    float xgv = (tid < 200) ? xg2[(size_t)brow * 200 + tid] : 0.0f;
    __syncthreads();

    for (int it = 0; it < CH + 2; ++it) {
        float pre = (tid < 200 && it + 1 < CH)
                  ? xg2[((size_t)(it + 1) * BATCH + brow) * 200 + tid] : 0.0f;

        if (tid < 200 && it < CH) {                 // L2 gates, step t0+it
            const float4* hv = (const float4*)h2_s;
            float a0 = xgv, a1 = 0.0f;
#define SCV(PV, WV, I) { float4 v = PV[I]; \
            a0 = fmaf(v.x, WV.x, a0); a1 = fmaf(v.y, WV.y, a1); \
            a0 = fmaf(v.z, WV.z, a0); a1 = fmaf(v.w, WV.w, a1); }
            SCV(hv,WA0,0) SCV(hv,WA1,1) SCV(hv,WA2,2) SCV(hv,WA3,3)
            SCV(hv,WA4,4) SCV(hv,WA5,5) SCV(hv,WA6,6) SCV(hv,WA7,7)
            SCV(hv,WA8,8) SCV(hv,WA9,9) SCV(hv,WA10,10) SCV(hv,WA11,11)
            SCV(hv,WA12,12)
            g2_s[tid] = a0 + a1;
        }

        if (tid >= 256 && tid < 356 && it >= 1 && it <= CH) {  // L3 gates
            const float4* xv = (const float4*)x3_s[(it - 1) & 1];
            const float4* hv = (const float4*)h3_s;
            float a0 = bias, a1 = 0.0f;
            SCV(xv,WA0,0) SCV(xv,WA1,1) SCV(xv,WA2,2) SCV(xv,WA3,3)
            SCV(xv,WA4,4) SCV(xv,WA5,5) SCV(xv,WA6,6) SCV(xv,WA7,7)
            SCV(xv,WA8,8) SCV(xv,WA9,9) SCV(xv,WA10,10) SCV(xv,WA11,11)
            SCV(xv,WA12,12)
            SCV(hv,WB0,0) SCV(hv,WB1,1) SCV(hv,WB2,2) SCV(hv,WB3,3)
            SCV(hv,WB4,4) SCV(hv,WB5,5) SCV(hv,WB6,6)
            g3_s[tid - 256] = a0 + a1;
        }

        if (tid == 370 && it >= 2) {               // linear
            const float4* hv = (const float4*)h3o_s[(it - 2) & 1];
            float a0 = bias, a1 = 0.0f;
            SCV(hv,WA0,0) SCV(hv,WA1,1) SCV(hv,WA2,2) SCV(hv,WA3,3)
            SCV(hv,WA4,4) SCV(hv,WA5,5) SCV(hv,WA6,6)
            out[(size_t)(t0 + it - 2) * BATCH + brow] = a0 + a1;
        }
#undef SCV
        __syncthreads();

        if (tid < 200) xgv = pre;

        if (tid < 50 && it < CH) {                  // L2 update
            float gi = g2_s[tid],       gf = g2_s[50 + tid];
            float gg = g2_s[100 + tid], go = g2_s[150 + tid];
            c2 = sigmoidf_(gf) * c2 + sigmoidf_(gi) * tanhf_(gg);
            float h = sigmoidf_(go) * tanhf_(c2);
            h2_s[tid] = h;
            x3_s[it & 1][tid] = h;
        }

        if (tid >= 256 && tid < 281 && it >= 1 && it <= CH) {  // L3 update
            int u = tid - 256;
            float gi = g3_s[u],      gf = g3_s[25 + u];
            float gg = g3_s[50 + u], go = g3_s[75 + u];
            c3 = sigmoidf_(gf) * c3 + sigmoidf_(gi) * tanhf_(gg);
            float h = sigmoidf_(go) * tanhf_(c3);
            h3_s[u] = h;
            h3o_s[(it - 1) & 1][u] = h;
        }
        __syncthreads();
    }

    if (tid < 50) {
        h2state[(size_t)brow * 50 + tid] = h2_s[tid];
        c2state[(size_t)brow * 50 + tid] = c2;
    }
    if (tid >= 256 && tid < 281) {
        int u = tid - 256;
        h3state[(size_t)brow * 25 + u] = h3_s[u];
        c3state[(size_t)brow * 25 + u] = c3;
    }
}

extern "C" void kernel_launch(void* const* d_in, const int* in_sizes, int n_in,
                              void* d_out, int out_size, void* d_ws, size_t ws_size,
                              hipStream_t stream)
{
    const float* x     = (const float*)d_in[0];
    const float* w_ih1 = (const float*)d_in[1];
    const float* w_hh1 = (const float*)d_in[2];
    const float* b_ih1 = (const float*)d_in[3];
    const float* b_hh1 = (const float*)d_in[4];
    const float* w_ih2 = (const float*)d_in[5];
    const float* w_hh2 = (const float*)d_in[6];
    const float* b_ih2 = (const float*)d_in[7];
    const float* b_hh2 = (const float*)d_in[8];
    const float* w_ih3 = (const float*)d_in[9];
    const float* w_hh3 = (const float*)d_in[10];
    const float* b_ih3 = (const float*)d_in[11];
    const float* b_hh3 = (const float*)d_in[12];
    const float* w_lin = (const float*)d_in[13];
    const float* b_lin = (const float*)d_in[14];
    float* out = (float*)d_out;

    const size_t state_bytes = (size_t)BATCH * (100 + 50 + 50 + 25 + 25) * sizeof(float);
    int CH = 0;
    for (int c = 128; c >= 8; c >>= 1) {
        size_t need = (size_t)c * BATCH * 700 * sizeof(float) + state_bytes;
        if (need <= ws_size) { CH = c; break; }
    }
    if (CH == 0) return;  // soft-fail: workspace too small

    char* ws = (char*)d_ws;
    float* xg1c    = (float*)ws;                                   // CH*B*400
    float* h1c     = xg1c + (size_t)CH * BATCH * 400;              // CH*B*100
    float* xg2c    = h1c  + (size_t)CH * BATCH * 100;              // CH*B*200
    float* c1state = xg2c + (size_t)CH * BATCH * 200;              // B*100
    float* h2state = c1state + (size_t)BATCH * 100;                // B*50
    float* c2state = h2state + (size_t)BATCH * 50;                 // B*50
    float* h3state = c2state + (size_t)BATCH * 50;                 // B*25
    float* c3state = h3state + (size_t)BATCH * 25;                 // B*25

    const int rowtiles = CH * BATCH / 64;

    for (int t0 = 0; t0 < T_STEPS; t0 += CH) {
        gemm1_kernel<<<rowtiles, 448, 0, stream>>>(
            x + (size_t)t0 * BATCH * 64, w_ih1, b_ih1, b_hh1, xg1c);
        scan1_kernel<<<BATCH / 2, 832, 0, stream>>>(xg1c, w_hh1, h1c, c1state, t0, CH);
        gemm2_kernel<<<rowtiles, 448, 0, stream>>>(h1c, w_ih2, b_ih2, b_hh2, xg2c);
        scan23_kernel<<<BATCH, 384, 0, stream>>>(
            xg2c, w_hh2, w_ih3, w_hh3, b_ih3, b_hh3, w_lin, b_lin, out,
            h2state, c2state, h3state, c3state, t0, CH);
    }
}